// Round 1
// baseline (759.003 us; speedup 1.0000x reference)
//
#include <hip/hip_runtime.h>
#include <hip/hip_bf16.h>
#include <stdint.h>

// coAttention: live compute after DCE:
//   q[b]   = Wp @ Q[b] + bp          (bias over last axis)
//   T[b]   = [W3|W4] @ [M[b]; q[b]] + b3
//   out[b] = relu(T[b]) * q[b]
// bf16 MFMA (16x16x32), fp32 accumulate. B=32, D=1024.

#define D_ 1024

typedef __attribute__((ext_vector_type(8))) short short8;
typedef __attribute__((ext_vector_type(4))) float floatx4;
typedef __attribute__((ext_vector_type(4))) unsigned short us4;

__device__ __forceinline__ unsigned short f2bf(float f) {
  union { float f; unsigned int u; } v; v.f = f;
  unsigned int u = v.u;
  unsigned int r = (u + 0x7FFFu + ((u >> 16) & 1u)) >> 16;  // RNE
  return (unsigned short)r;
}

__device__ __forceinline__ float bf2f(unsigned short h) {
  union { unsigned int u; float f; } v; v.u = ((unsigned int)h) << 16;
  return v.f;
}

// async global->LDS, 16B per lane; LDS dest is wave-uniform base + lane*16
__device__ __forceinline__ void async_load16(const void* g, void* l) {
  __builtin_amdgcn_global_load_lds(
      (const __attribute__((address_space(1))) unsigned int*)g,
      (__attribute__((address_space(3))) unsigned int*)l, 16, 0, 0);
}

// ---------------- Pass 0a: transpose + fp32->bf16 convert (1024x1024 per batch)
// out[b][c][r] = bf16(in[b][r][c])
__global__ __launch_bounds__(256) void transpose_cvt(
    const float* __restrict__ in, unsigned short* __restrict__ out) {
  __shared__ float tile[64][65];
  const int b = blockIdx.z;
  const long base = ((long)b) << 20;
  const int r0 = blockIdx.y * 64, c0 = blockIdx.x * 64;
  const int t = threadIdx.x;
  const int tr = t >> 4, tc4 = (t & 15) * 4;
#pragma unroll
  for (int p = 0; p < 4; ++p) {
    const int row = p * 16 + tr;
    const float4 v = *(const float4*)&in[base + (long)(r0 + row) * D_ + c0 + tc4];
    tile[row][tc4 + 0] = v.x; tile[row][tc4 + 1] = v.y;
    tile[row][tc4 + 2] = v.z; tile[row][tc4 + 3] = v.w;
  }
  __syncthreads();
#pragma unroll
  for (int p = 0; p < 4; ++p) {
    const int c = p * 16 + tr;
    us4 pk;
    pk.x = f2bf(tile[tc4 + 0][c]);
    pk.y = f2bf(tile[tc4 + 1][c]);
    pk.z = f2bf(tile[tc4 + 2][c]);
    pk.w = f2bf(tile[tc4 + 3][c]);
    *(us4*)&out[base + (long)(c0 + c) * D_ + r0 + tc4] = pk;
  }
}

// ---------------- Pass 0b: convert weights; A2 = [W3 | W4] row-major 1024x2048
__global__ __launch_bounds__(256) void convert_weights(
    const float* __restrict__ Wp, const float* __restrict__ W3,
    const float* __restrict__ W4, unsigned short* __restrict__ Wpb,
    unsigned short* __restrict__ A2) {
  const int i = blockIdx.x * 256 + threadIdx.x;  // 262144 float4 groups exactly
  const long e = (long)i * 4;
  const int row = (int)(e >> 10);
  const int col = (int)(e & 1023);
  const float4 a = ((const float4*)Wp)[i];
  us4 pa; pa.x = f2bf(a.x); pa.y = f2bf(a.y); pa.z = f2bf(a.z); pa.w = f2bf(a.w);
  ((us4*)Wpb)[i] = pa;
  const float4 w3 = ((const float4*)W3)[i];
  us4 p3; p3.x = f2bf(w3.x); p3.y = f2bf(w3.y); p3.z = f2bf(w3.z); p3.w = f2bf(w3.w);
  *(us4*)&A2[(long)row * 2048 + col] = p3;
  const float4 w4 = ((const float4*)W4)[i];
  us4 p4; p4.x = f2bf(w4.x); p4.y = f2bf(w4.y); p4.z = f2bf(w4.z); p4.w = f2bf(w4.w);
  *(us4*)&A2[(long)row * 2048 + 1024 + col] = p4;
}

// ---------------- Pass 1: q^T[b][k][i] = bf16( (Wp @ Q[b])[i][k] + bp[k] )
// A = Wpb (1024x1024 bf16, row-major i,j), B^T = Qt[b] (k-major, 1024x1024)
__global__ __launch_bounds__(256) void gemm1(
    const unsigned short* __restrict__ Wpb,
    const unsigned short* __restrict__ Qt,
    const float* __restrict__ bp,
    unsigned short* __restrict__ qt) {
  __shared__ __align__(16) unsigned short As[128 * 64];
  __shared__ __align__(16) unsigned short Bs[128 * 64];
  const int lane = threadIdx.x & 63;
  const int wave = threadIdx.x >> 6;
  const int b = blockIdx.z;
  const int m0 = blockIdx.y * 128, n0 = blockIdx.x * 128;
  const long bb = ((long)b) << 20;
  const int wm = (wave >> 1) * 64, wn = (wave & 1) * 64;

  const int srow = wave * 32 + (lane >> 3);   // staging row within tile
  const int scol = (lane & 7) * 8;            // staging col (bf16 elems)

  const unsigned short* ag = Wpb + (long)(m0 + srow) * D_ + scol;
  const unsigned short* bg = Qt + bb + (long)(n0 + srow) * D_ + scol;

  floatx4 acc[4][4] = {};

  for (int kk = 0; kk < D_; kk += 64) {
    if (kk) __syncthreads();
#pragma unroll
    for (int t = 0; t < 4; ++t) {
      async_load16(ag + (long)t * 8 * D_ + kk, &As[(wave * 32 + t * 8) * 64]);
      async_load16(bg + (long)t * 8 * D_ + kk, &Bs[(wave * 32 + t * 8) * 64]);
    }
    __syncthreads();
#pragma unroll
    for (int k2 = 0; k2 < 64; k2 += 32) {
      const int krd = k2 + (lane >> 4) * 8;
      short8 af[4], bf[4];
#pragma unroll
      for (int mt = 0; mt < 4; ++mt)
        af[mt] = *(const short8*)&As[(wm + mt * 16 + (lane & 15)) * 64 + krd];
#pragma unroll
      for (int nt = 0; nt < 4; ++nt)
        bf[nt] = *(const short8*)&Bs[(wn + nt * 16 + (lane & 15)) * 64 + krd];
#pragma unroll
      for (int mt = 0; mt < 4; ++mt)
#pragma unroll
        for (int nt = 0; nt < 4; ++nt)
          acc[mt][nt] = __builtin_amdgcn_mfma_f32_16x16x32_bf16(
              af[mt], bf[nt], acc[mt][nt], 0, 0, 0);
    }
  }

  // epilogue: +bp[col], write q^T (k-major) bf16. C/D: col=lane&15, row=quad*4+reg
  const int quad = lane >> 4;
#pragma unroll
  for (int nt = 0; nt < 4; ++nt) {
    const int col = n0 + wn + nt * 16 + (lane & 15);
    const float bias = bp[col];
#pragma unroll
    for (int mt = 0; mt < 4; ++mt) {
      const int row = m0 + wm + mt * 16 + quad * 4;
      const floatx4 v = acc[mt][nt];
      us4 pk;
      pk.x = f2bf(v.x + bias); pk.y = f2bf(v.y + bias);
      pk.z = f2bf(v.z + bias); pk.w = f2bf(v.w + bias);
      *(us4*)&qt[bb + (long)col * D_ + row] = pk;
    }
  }
}

// ---------------- Pass 2: out = relu([W3|W4] @ [M;q] + b3) * q
// A = A2 (1024x2048), B^T rows: j<1024 -> Mt[b][n][j]; j>=1024 -> qt[b][n][j-1024]
__global__ __launch_bounds__(256) void gemm2(
    const unsigned short* __restrict__ A2,
    const unsigned short* __restrict__ Mt,
    const unsigned short* __restrict__ qt,
    const float* __restrict__ b3,
    float* __restrict__ out) {
  __shared__ __align__(16) unsigned short As[128 * 64];
  __shared__ __align__(16) unsigned short Bs[128 * 64];
  const int lane = threadIdx.x & 63;
  const int wave = threadIdx.x >> 6;
  const int b = blockIdx.z;
  const int m0 = blockIdx.y * 128, n0 = blockIdx.x * 128;
  const long bb = ((long)b) << 20;
  const int wm = (wave >> 1) * 64, wn = (wave & 1) * 64;

  const int srow = wave * 32 + (lane >> 3);
  const int scol = (lane & 7) * 8;

  const unsigned short* ag = A2 + (long)(m0 + srow) * 2048 + scol;
  const unsigned short* bg1 = Mt + bb + (long)(n0 + srow) * D_ + scol;
  const unsigned short* bg2 = qt + bb + (long)(n0 + srow) * D_ + scol;

  floatx4 acc[4][4] = {};

  for (int kk = 0; kk < 2048; kk += 64) {
    if (kk) __syncthreads();
    const unsigned short* bg = (kk < 1024) ? (bg1 + kk) : (bg2 + (kk - 1024));
#pragma unroll
    for (int t = 0; t < 4; ++t) {
      async_load16(ag + (long)t * 8 * 2048 + kk, &As[(wave * 32 + t * 8) * 64]);
      async_load16(bg + (long)t * 8 * D_, &Bs[(wave * 32 + t * 8) * 64]);
    }
    __syncthreads();
#pragma unroll
    for (int k2 = 0; k2 < 64; k2 += 32) {
      const int krd = k2 + (lane >> 4) * 8;
      short8 af[4], bf[4];
#pragma unroll
      for (int mt = 0; mt < 4; ++mt)
        af[mt] = *(const short8*)&As[(wm + mt * 16 + (lane & 15)) * 64 + krd];
#pragma unroll
      for (int nt = 0; nt < 4; ++nt)
        bf[nt] = *(const short8*)&Bs[(wn + nt * 16 + (lane & 15)) * 64 + krd];
#pragma unroll
      for (int mt = 0; mt < 4; ++mt)
#pragma unroll
        for (int nt = 0; nt < 4; ++nt)
          acc[mt][nt] = __builtin_amdgcn_mfma_f32_16x16x32_bf16(
              af[mt], bf[nt], acc[mt][nt], 0, 0, 0);
    }
  }

  // epilogue: relu(acc + b3[col]) * q[row][col]  (q read from k-major qt)
  const int quad = lane >> 4;
#pragma unroll
  for (int nt = 0; nt < 4; ++nt) {
    const int col = n0 + wn + nt * 16 + (lane & 15);
    const float b3v = b3[col];
#pragma unroll
    for (int mt = 0; mt < 4; ++mt) {
      const int row = m0 + wm + mt * 16 + quad * 4;
      const floatx4 v = acc[mt][nt];
      const us4 qv = *(const us4*)&qt[bb + (long)col * D_ + row];
      float t0 = fmaxf(v.x + b3v, 0.0f);
      float t1 = fmaxf(v.y + b3v, 0.0f);
      float t2 = fmaxf(v.z + b3v, 0.0f);
      float t3 = fmaxf(v.w + b3v, 0.0f);
      out[bb + (long)(row + 0) * D_ + col] = t0 * bf2f(qv.x);
      out[bb + (long)(row + 1) * D_ + col] = t1 * bf2f(qv.y);
      out[bb + (long)(row + 2) * D_ + col] = t2 * bf2f(qv.z);
      out[bb + (long)(row + 3) * D_ + col] = t3 * bf2f(qv.w);
    }
  }
}

extern "C" void kernel_launch(void* const* d_in, const int* in_sizes, int n_in,
                              void* d_out, int out_size, void* d_ws, size_t ws_size,
                              hipStream_t stream) {
  const float* Q  = (const float*)d_in[1];
  const float* M  = (const float*)d_in[2];
  const float* Wp = (const float*)d_in[4];
  const float* bp = (const float*)d_in[5];
  const float* W3 = (const float*)d_in[6];
  const float* W4 = (const float*)d_in[7];
  const float* b3 = (const float*)d_in[8];
  float* out = (float*)d_out;

  char* ws = (char*)d_ws;
  unsigned short* qt  = (unsigned short*)(ws);                 // 64 MiB: q^T bf16
  unsigned short* Qt  = (unsigned short*)(ws + (64l  << 20));  // 64 MiB: Q^T bf16
  unsigned short* Mt  = (unsigned short*)(ws + (128l << 20));  // 64 MiB: M^T bf16
  unsigned short* Wpb = (unsigned short*)(ws + (192l << 20));  // 2 MiB
  unsigned short* A2  = (unsigned short*)(ws + (194l << 20));  // 4 MiB: [W3|W4]

  dim3 tgrid(16, 16, 32);
  transpose_cvt<<<tgrid, 256, 0, stream>>>(Q, Qt);
  transpose_cvt<<<tgrid, 256, 0, stream>>>(M, Mt);
  convert_weights<<<1024, 256, 0, stream>>>(Wp, W3, W4, Wpb, A2);

  dim3 ggrid(8, 8, 32);
  gemm1<<<ggrid, 256, 0, stream>>>(Wpb, Qt, bp, qt);
  gemm2<<<ggrid, 256, 0, stream>>>(A2, Mt, qt, b3, out);
}